// Round 1
// baseline (1987.956 us; speedup 1.0000x reference)
//
#include <hip/hip_runtime.h>
#include <math.h>
#include <float.h>

#define NB    65536
#define DIN   1408
#define PDIM  256
#define KCB   64
#define TAU   3e-4f

// ---------------- workspace layout ----------------
// [0]          int   cnt (ambiguous-row counter)   (zeroed via memsetAsync)
// [64]         int   cand[NB]
// [262208]     int   list[NB]
// [524352]     double partials[NB]
// [1048832]    float g[NB*PDIM]
#define OFF_CNT   0
#define OFF_CAND  64
#define OFF_LIST  262208
#define OFF_PART  524352
#define OFF_G     1048832

static __device__ __forceinline__ float wave_sum(float v) {
#pragma unroll
  for (int m = 32; m; m >>= 1) v += __shfl_xor(v, m, 64);
  return v;
}

// K1: inverse L2 norm of each z_frame row. 4 rows/block (wave per row).
__global__ __launch_bounds__(256) void k1_row_norm(const float* __restrict__ A,
                                                   float* __restrict__ inv_norm) {
  int wave = threadIdx.x >> 6, lane = threadIdx.x & 63;
  int row = blockIdx.x * 4 + wave;
  const float4* a4 = (const float4*)(A + (size_t)row * DIN);
  float s = 0.f;
  for (int i = lane; i < DIN / 4; i += 64) {
    float4 v = a4[i];
    s += v.x * v.x + v.y * v.y + v.z * v.z + v.w * v.w;
  }
  s = wave_sum(s);
  if (lane == 0) inv_norm[row] = 1.0f / fmaxf(sqrtf(s), 1e-12f);
}

// K2: g = z_frame @ W  (raw rows; row scaling deferred to epilogue).
// block: 64 rows x 256 cols, 256 threads, BK=16.
// thread t: tx=t&63 -> cols 4tx..4tx+3 ; ty=t>>6 -> rows 16ty..16ty+15.
__global__ __launch_bounds__(256) void k2_gemm(const float* __restrict__ A,
                                               const float* __restrict__ W,
                                               float* __restrict__ g) {
  __shared__ float As[16][68];    // transposed A tile [k][row], padded
  __shared__ float Ws[16][256];   // W tile [k][col]
  const int t = threadIdx.x;
  const int tx = t & 63, ty = t >> 6;
  const int row0 = blockIdx.x * 64;
  const int arow = t >> 2, aq = (t & 3) << 2;   // staging: row, k-quad
  const float* Aptr = A + (size_t)(row0 + arow) * DIN + aq;

  float acc[64];
#pragma unroll
  for (int i = 0; i < 64; ++i) acc[i] = 0.f;

  for (int k0 = 0; k0 < DIN; k0 += 16) {
    float4 av = *(const float4*)(Aptr + k0);
    float4 wv[4];
#pragma unroll
    for (int r = 0; r < 4; ++r) {
      int f4 = t + (r << 8);                       // float4 index in [0,1024)
      wv[r] = *(const float4*)(W + (size_t)(k0 + (f4 >> 6)) * PDIM + ((f4 & 63) << 2));
    }
    __syncthreads();
    As[aq + 0][arow] = av.x;
    As[aq + 1][arow] = av.y;
    As[aq + 2][arow] = av.z;
    As[aq + 3][arow] = av.w;
#pragma unroll
    for (int r = 0; r < 4; ++r) {
      int f4 = t + (r << 8);
      *(float4*)&Ws[f4 >> 6][(f4 & 63) << 2] = wv[r];
    }
    __syncthreads();
#pragma unroll
    for (int k = 0; k < 16; ++k) {
      float4 w4 = *(const float4*)&Ws[k][tx << 2];
      const float4* ap = (const float4*)&As[k][ty << 4];
      float4 a0 = ap[0], a1 = ap[1], a2 = ap[2], a3 = ap[3];
      float wa[4] = {w4.x, w4.y, w4.z, w4.w};
      float aa[16] = {a0.x, a0.y, a0.z, a0.w, a1.x, a1.y, a1.z, a1.w,
                      a2.x, a2.y, a2.z, a2.w, a3.x, a3.y, a3.z, a3.w};
#pragma unroll
      for (int i = 0; i < 16; ++i)
#pragma unroll
        for (int j = 0; j < 4; ++j)
          acc[i * 4 + j] = fmaf(aa[i], wa[j], acc[i * 4 + j]);
    }
  }
#pragma unroll
  for (int i = 0; i < 16; ++i) {
    float4 o = {acc[i * 4 + 0], acc[i * 4 + 1], acc[i * 4 + 2], acc[i * 4 + 3]};
    *(float4*)(g + (size_t)(row0 + (ty << 4) + i) * PDIM + (tx << 2)) = o;
  }
}

// K3: per-row epilogue: h = g*s + b -> LayerNorm -> l2norm -> z (parked in d_out),
// fp32 dists to codebook, top-2 argmin, flag ambiguous rows. Wave per row.
__global__ __launch_bounds__(256) void k3_epilogue(const float* __restrict__ g,
                                                   const float* __restrict__ inv_norm,
                                                   const float* __restrict__ bvec,
                                                   const float* __restrict__ gamma,
                                                   const float* __restrict__ beta,
                                                   const float* __restrict__ C,
                                                   float* __restrict__ z_out,
                                                   int* __restrict__ cand,
                                                   int* __restrict__ list,
                                                   int* __restrict__ cnt) {
  __shared__ float zsh[4][260];
  const int wave = threadIdx.x >> 6, lane = threadIdx.x & 63;
  const int row = blockIdx.x * 4 + wave;

  float4 gv = *(const float4*)(g + (size_t)row * PDIM + (lane << 2));
  const float s = inv_norm[row];
  float4 bv = *(const float4*)(bvec + (lane << 2));
  float h0 = gv.x * s + bv.x, h1 = gv.y * s + bv.y;
  float h2 = gv.z * s + bv.z, h3 = gv.w * s + bv.w;

  float mu = wave_sum(h0 + h1 + h2 + h3) * (1.0f / 256.0f);
  float d0 = h0 - mu, d1 = h1 - mu, d2 = h2 - mu, d3 = h3 - mu;
  float var = wave_sum(d0 * d0 + d1 * d1 + d2 * d2 + d3 * d3) * (1.0f / 256.0f);
  float invs = 1.0f / sqrtf(var + 1e-5f);
  float4 gm = *(const float4*)(gamma + (lane << 2));
  float4 bt = *(const float4*)(beta + (lane << 2));
  float zp0 = d0 * invs * gm.x + bt.x, zp1 = d1 * invs * gm.y + bt.y;
  float zp2 = d2 * invs * gm.z + bt.z, zp3 = d3 * invs * gm.w + bt.w;
  float nz = wave_sum(zp0 * zp0 + zp1 * zp1 + zp2 * zp2 + zp3 * zp3);
  float zn = 1.0f / fmaxf(sqrtf(nz), 1e-12f);
  float z0 = zp0 * zn, z1 = zp1 * zn, z2 = zp2 * zn, z3 = zp3 * zn;

  float4 zf = {z0, z1, z2, z3};
  *(float4*)(z_out + (size_t)row * PDIM + (lane << 2)) = zf;  // park z in d_out
  float zz = wave_sum(z0 * z0 + z1 * z1 + z2 * z2 + z3 * z3);

  *(float4*)&zsh[wave][lane << 2] = zf;
  __syncthreads();

  // lane == codebook index k
  const float4* crow = (const float4*)(C + (size_t)lane * PDIM);
  float p = 0.f, cc = 0.f;
#pragma unroll 8
  for (int c4 = 0; c4 < 64; ++c4) {
    float4 cv = crow[c4];
    float4 zv = *(const float4*)&zsh[wave][c4 << 2];
    p += zv.x * cv.x + zv.y * cv.y + zv.z * cv.z + zv.w * cv.w;
    cc += cv.x * cv.x + cv.y * cv.y + cv.z * cv.z + cv.w * cv.w;
  }
  float dist = zz - 2.0f * p + cc;

  // top-2 butterfly reduce, first-index tiebreak on the min
  float b1 = dist; int i1 = lane; float b2 = FLT_MAX;
#pragma unroll
  for (int m = 32; m; m >>= 1) {
    float ob1 = __shfl_xor(b1, m, 64);
    int oi1 = __shfl_xor(i1, m, 64);
    float ob2 = __shfl_xor(b2, m, 64);
    if (ob1 < b1 || (ob1 == b1 && oi1 < i1)) {
      b2 = fminf(b1, ob2);
      b1 = ob1; i1 = oi1;
    } else {
      b2 = fminf(b2, ob1);
    }
  }
  if (lane == 0) {
    cand[row] = i1;
    if (b2 - b1 < TAU) {
      int w = atomicAdd(cnt, 1);
      list[w] = row;
    }
  }
}

// K4: fp64 recompute of flagged rows (index only).
__global__ __launch_bounds__(256) void k4_refine(const float* __restrict__ A,
                                                 const float* __restrict__ W,
                                                 const float* __restrict__ bvec,
                                                 const float* __restrict__ gamma,
                                                 const float* __restrict__ beta,
                                                 const float* __restrict__ C,
                                                 const int* __restrict__ list,
                                                 const int* __restrict__ cnt,
                                                 int* __restrict__ cand) {
  __shared__ double xs[DIN];
  __shared__ double red[256];
  __shared__ double zd[PDIM];
  const int t = threadIdx.x;
  const int n = *cnt;
  for (int it = blockIdx.x; it < n; it += gridDim.x) {
    const int row = list[it];
    __syncthreads();
    for (int i = t; i < DIN; i += 256) xs[i] = (double)A[(size_t)row * DIN + i];
    __syncthreads();
    double s = 0.0;
    for (int i = t; i < DIN; i += 256) s += xs[i] * xs[i];
    red[t] = s; __syncthreads();
    for (int m = 128; m; m >>= 1) { if (t < m) red[t] += red[t + m]; __syncthreads(); }
    const double inv = 1.0 / fmax(sqrt(red[0]), 1e-12);

    double gj = 0.0;
#pragma unroll 8
    for (int k = 0; k < DIN; ++k) gj += xs[k] * (double)W[(size_t)k * PDIM + t];
    const double h = gj * inv + (double)bvec[t];

    __syncthreads(); red[t] = h; __syncthreads();
    for (int m = 128; m; m >>= 1) { if (t < m) red[t] += red[t + m]; __syncthreads(); }
    const double mu = red[0] * (1.0 / 256.0);
    const double d = h - mu;
    __syncthreads(); red[t] = d * d; __syncthreads();
    for (int m = 128; m; m >>= 1) { if (t < m) red[t] += red[t + m]; __syncthreads(); }
    const double invs = 1.0 / sqrt(red[0] * (1.0 / 256.0) + 1e-5);
    const double zp = d * invs * (double)gamma[t] + (double)beta[t];
    __syncthreads(); red[t] = zp * zp; __syncthreads();
    for (int m = 128; m; m >>= 1) { if (t < m) red[t] += red[t + m]; __syncthreads(); }
    const double zn = 1.0 / fmax(sqrt(red[0]), 1e-12);
    const double z = zp * zn;
    zd[t] = z;
    __syncthreads(); red[t] = z * z; __syncthreads();
    for (int m = 128; m; m >>= 1) { if (t < m) red[t] += red[t + m]; __syncthreads(); }
    const double zz = red[0];
    __syncthreads();
    if (t < KCB) {
      double p = 0.0, cc = 0.0;
      for (int c = 0; c < PDIM; ++c) {
        double cv = (double)C[(size_t)t * PDIM + c];
        p += zd[c] * cv; cc += cv * cv;
      }
      red[t] = zz - 2.0 * p + cc;
    }
    __syncthreads();
    if (t == 0) {
      double best = red[0]; int bi = 0;
      for (int k = 1; k < KCB; ++k) if (red[k] < best) { best = red[k]; bi = k; }
      cand[row] = bi;
    }
    __syncthreads();
  }
}

// K5: z_q_st = z + (c - z), indices as float, per-row loss partial. Block per row.
__global__ __launch_bounds__(256) void k5_output(const float* __restrict__ C,
                                                 const int* __restrict__ cand,
                                                 float* __restrict__ out,
                                                 double* __restrict__ partials) {
  __shared__ float lred[4];
  const int row = blockIdx.x;
  const int t = threadIdx.x;
  const int idx = cand[row];
  const float z = out[(size_t)row * PDIM + t];
  const float c = C[(size_t)idx * PDIM + t];
  const float diff = c - z;
  out[(size_t)row * PDIM + t] = z + diff;
  if (t == 0) out[(size_t)NB * PDIM + row] = (float)idx;
  float l = wave_sum(diff * diff);
  const int wave = t >> 6, lane = t & 63;
  if (lane == 0) lred[wave] = l;
  __syncthreads();
  if (t == 0)
    partials[row] = (double)lred[0] + (double)lred[1] + (double)lred[2] + (double)lred[3];
}

// K6: reduce loss partials, write scalar.
__global__ __launch_bounds__(256) void k6_finalize(const double* __restrict__ partials,
                                                   float* __restrict__ out) {
  __shared__ double red[256];
  const int t = threadIdx.x;
  double s = 0.0;
  for (int i = t; i < NB; i += 256) s += partials[i];
  red[t] = s; __syncthreads();
  for (int m = 128; m; m >>= 1) { if (t < m) red[t] += red[t + m]; __syncthreads(); }
  if (t == 0)
    out[(size_t)NB * PDIM + NB] = (float)(0.25 * red[0] / ((double)NB * (double)PDIM));
}

extern "C" void kernel_launch(void* const* d_in, const int* in_sizes, int n_in,
                              void* d_out, int out_size, void* d_ws, size_t ws_size,
                              hipStream_t stream) {
  const float* z_frame  = (const float*)d_in[0];
  const float* W        = (const float*)d_in[1];
  const float* bvec     = (const float*)d_in[2];
  const float* gamma    = (const float*)d_in[3];
  const float* beta     = (const float*)d_in[4];
  const float* codebook = (const float*)d_in[5];
  float* out = (float*)d_out;

  char* ws = (char*)d_ws;
  int*    cnt      = (int*)(ws + OFF_CNT);
  int*    cand     = (int*)(ws + OFF_CAND);
  int*    list     = (int*)(ws + OFF_LIST);
  double* partials = (double*)(ws + OFF_PART);
  float*  g        = (float*)(ws + OFF_G);
  float*  inv_norm = (float*)(ws + OFF_CNT + 4096);  // reuse head pad region? no:
  // inv_norm needs NB floats = 256KB; place it after g.
  inv_norm = (float*)(ws + OFF_G + (size_t)NB * PDIM * sizeof(float));

  hipMemsetAsync(ws + OFF_CNT, 0, 64, stream);

  k1_row_norm<<<NB / 4, 256, 0, stream>>>(z_frame, inv_norm);
  k2_gemm<<<NB / 64, 256, 0, stream>>>(z_frame, W, g);
  k3_epilogue<<<NB / 4, 256, 0, stream>>>(g, inv_norm, bvec, gamma, beta, codebook,
                                          out, cand, list, cnt);
  k4_refine<<<256, 256, 0, stream>>>(z_frame, W, bvec, gamma, beta, codebook,
                                     list, cnt, cand);
  k5_output<<<NB, 256, 0, stream>>>(codebook, cand, out, partials);
  k6_finalize<<<1, 256, 0, stream>>>(partials, out);
}

// Round 2
// 1629.230 us; speedup vs baseline: 1.2202x; 1.2202x over previous
//
#include <hip/hip_runtime.h>
#include <math.h>
#include <float.h>

#define NB    65536
#define DIN   1408
#define PDIM  256
#define KCB   64
#define TAU   3e-4f

// ---------------- workspace layout ----------------
// [0]       int    cnt (ambiguous-row counter; zeroed via memsetAsync)
// [64]      int    cand[NB]
// [262208]  int    list[NB]
// [524352]  double partials[NB/4]        (16384 * 8 = 131072 B)
// [1048832] float  g[NB*PDIM]
#define OFF_CNT   0
#define OFF_CAND  64
#define OFF_LIST  262208
#define OFF_PART  524352
#define OFF_G     1048832

static __device__ __forceinline__ float wave_sum(float v) {
#pragma unroll
  for (int m = 32; m; m >>= 1) v += __shfl_xor(v, m, 64);
  return v;
}

// K2: g = l2norm(z_frame) @ W, with the row inverse-norm computed on the fly
// from the staging loads (each A element is loaded exactly once per block).
// block: 64 rows x 256 cols, 256 threads, BK=16.
// thread t: tx=t&63 -> cols 4tx..4tx+3 ; ty=t>>6 -> rows 16ty..16ty+15.
__global__ __launch_bounds__(256, 2) void k2_gemm(const float* __restrict__ A,
                                                  const float* __restrict__ W,
                                                  float* __restrict__ g) {
  __shared__ float As[16][68];    // transposed A tile [k][row], padded
  __shared__ float Ws[16][256];   // W tile [k][col]
  __shared__ float rn[64];        // per-row sum of squares
  const int t = threadIdx.x;
  const int tx = t & 63, ty = t >> 6;
  const int row0 = blockIdx.x * 64;
  const int arow = t >> 2, aq = (t & 3) << 2;   // staging: row, k-quad
  const float* Aptr = A + (size_t)(row0 + arow) * DIN + aq;

  float acc[64];
#pragma unroll
  for (int i = 0; i < 64; ++i) acc[i] = 0.f;
  float ss = 0.f;   // partial sum-of-squares for row `arow`

  for (int k0 = 0; k0 < DIN; k0 += 16) {
    float4 av = *(const float4*)(Aptr + k0);
    float4 wv[4];
#pragma unroll
    for (int r = 0; r < 4; ++r) {
      int f4 = t + (r << 8);                       // float4 index in [0,1024)
      wv[r] = *(const float4*)(W + (size_t)(k0 + (f4 >> 6)) * PDIM + ((f4 & 63) << 2));
    }
    ss += av.x * av.x + av.y * av.y + av.z * av.z + av.w * av.w;
    __syncthreads();
    As[aq + 0][arow] = av.x;
    As[aq + 1][arow] = av.y;
    As[aq + 2][arow] = av.z;
    As[aq + 3][arow] = av.w;
#pragma unroll
    for (int r = 0; r < 4; ++r) {
      int f4 = t + (r << 8);
      *(float4*)&Ws[f4 >> 6][(f4 & 63) << 2] = wv[r];
    }
    __syncthreads();
#pragma unroll
    for (int k = 0; k < 16; ++k) {
      float4 w4 = *(const float4*)&Ws[k][tx << 2];
      const float4* ap = (const float4*)&As[k][ty << 4];
      float4 a0 = ap[0], a1 = ap[1], a2 = ap[2], a3 = ap[3];
      float wa[4] = {w4.x, w4.y, w4.z, w4.w};
      float aa[16] = {a0.x, a0.y, a0.z, a0.w, a1.x, a1.y, a1.z, a1.w,
                      a2.x, a2.y, a2.z, a2.w, a3.x, a3.y, a3.z, a3.w};
#pragma unroll
      for (int i = 0; i < 16; ++i)
#pragma unroll
        for (int j = 0; j < 4; ++j)
          acc[i * 4 + j] = fmaf(aa[i], wa[j], acc[i * 4 + j]);
    }
  }

  // reduce the 4 staging partials per row (threads 4r..4r+3 are wave-adjacent)
  ss += __shfl_xor(ss, 1, 64);
  ss += __shfl_xor(ss, 2, 64);
  if ((t & 3) == 0) rn[arow] = ss;
  __syncthreads();

#pragma unroll
  for (int i = 0; i < 16; ++i) {
    const int r = (ty << 4) + i;
    const float inv = 1.0f / fmaxf(sqrtf(rn[r]), 1e-12f);
    float4 o = {acc[i * 4 + 0] * inv, acc[i * 4 + 1] * inv,
                acc[i * 4 + 2] * inv, acc[i * 4 + 3] * inv};
    *(float4*)(g + (size_t)(row0 + r) * PDIM + (tx << 2)) = o;
  }
}

// K3: per-row epilogue: h = g + b -> LayerNorm -> l2norm -> z,
// fp32 dists to codebook, top-2 argmin, flag ambiguous rows,
// write out row = codebook[i1] (straight-through forward value == z_q),
// write index, per-block fp64 loss partial. Wave per row, 4 rows/block.
__global__ __launch_bounds__(256) void k3_epilogue(const float* __restrict__ g,
                                                   const float* __restrict__ bvec,
                                                   const float* __restrict__ gamma,
                                                   const float* __restrict__ beta,
                                                   const float* __restrict__ C,
                                                   float* __restrict__ out,
                                                   int* __restrict__ cand,
                                                   int* __restrict__ list,
                                                   int* __restrict__ cnt,
                                                   double* __restrict__ partials) {
  __shared__ float zsh[4][260];
  __shared__ float lp[4];
  const int wave = threadIdx.x >> 6, lane = threadIdx.x & 63;
  const int row = blockIdx.x * 4 + wave;

  float4 gv = *(const float4*)(g + (size_t)row * PDIM + (lane << 2));
  float4 bv = *(const float4*)(bvec + (lane << 2));
  float h0 = gv.x + bv.x, h1 = gv.y + bv.y;
  float h2 = gv.z + bv.z, h3 = gv.w + bv.w;

  float mu = wave_sum(h0 + h1 + h2 + h3) * (1.0f / 256.0f);
  float d0 = h0 - mu, d1 = h1 - mu, d2 = h2 - mu, d3 = h3 - mu;
  float var = wave_sum(d0 * d0 + d1 * d1 + d2 * d2 + d3 * d3) * (1.0f / 256.0f);
  float invs = 1.0f / sqrtf(var + 1e-5f);
  float4 gm = *(const float4*)(gamma + (lane << 2));
  float4 bt = *(const float4*)(beta + (lane << 2));
  float zp0 = d0 * invs * gm.x + bt.x, zp1 = d1 * invs * gm.y + bt.y;
  float zp2 = d2 * invs * gm.z + bt.z, zp3 = d3 * invs * gm.w + bt.w;
  float nz = wave_sum(zp0 * zp0 + zp1 * zp1 + zp2 * zp2 + zp3 * zp3);
  float zn = 1.0f / fmaxf(sqrtf(nz), 1e-12f);
  float z0 = zp0 * zn, z1 = zp1 * zn, z2 = zp2 * zn, z3 = zp3 * zn;

  float4 zf = {z0, z1, z2, z3};
  float zz = wave_sum(z0 * z0 + z1 * z1 + z2 * z2 + z3 * z3);

  *(float4*)&zsh[wave][lane << 2] = zf;
  __syncthreads();

  // lane == codebook index k
  const float4* crow = (const float4*)(C + (size_t)lane * PDIM);
  float p = 0.f, cc = 0.f;
#pragma unroll 8
  for (int c4 = 0; c4 < 64; ++c4) {
    float4 cv = crow[c4];
    float4 zv = *(const float4*)&zsh[wave][c4 << 2];
    p += zv.x * cv.x + zv.y * cv.y + zv.z * cv.z + zv.w * cv.w;
    cc += cv.x * cv.x + cv.y * cv.y + cv.z * cv.z + cv.w * cv.w;
  }
  float dist = zz - 2.0f * p + cc;

  // top-2 butterfly reduce, first-index tiebreak on the min
  float b1 = dist; int i1 = lane; float b2 = FLT_MAX;
#pragma unroll
  for (int m = 32; m; m >>= 1) {
    float ob1 = __shfl_xor(b1, m, 64);
    int oi1 = __shfl_xor(i1, m, 64);
    float ob2 = __shfl_xor(b2, m, 64);
    if (ob1 < b1 || (ob1 == b1 && oi1 < i1)) {
      b2 = fminf(b1, ob2);
      b1 = ob1; i1 = oi1;
    } else {
      b2 = fminf(b2, ob1);
    }
  }
  if (lane == 0) {
    cand[row] = i1;
    if (b2 - b1 < TAU) {
      int w = atomicAdd(cnt, 1);
      list[w] = row;
    }
  }
  i1 = __shfl(i1, 0, 64);

  // straight-through forward value: out row = codebook[i1]; loss partial
  float4 cv = *(const float4*)(C + (size_t)i1 * PDIM + (lane << 2));
  *(float4*)(out + (size_t)row * PDIM + (lane << 2)) = cv;
  float e0 = cv.x - z0, e1 = cv.y - z1, e2 = cv.z - z2, e3 = cv.w - z3;
  float l = wave_sum(e0 * e0 + e1 * e1 + e2 * e2 + e3 * e3);
  if (lane == 0) {
    out[(size_t)NB * PDIM + row] = (float)i1;
    lp[wave] = l;
  }
  __syncthreads();
  if (threadIdx.x == 0)
    partials[blockIdx.x] =
        (double)lp[0] + (double)lp[1] + (double)lp[2] + (double)lp[3];
}

// K4: fp64 recompute of flagged rows; fix index, output row, loss partial.
__global__ __launch_bounds__(256) void k4_refine(const float* __restrict__ A,
                                                 const float* __restrict__ W,
                                                 const float* __restrict__ bvec,
                                                 const float* __restrict__ gamma,
                                                 const float* __restrict__ beta,
                                                 const float* __restrict__ C,
                                                 const int* __restrict__ list,
                                                 const int* __restrict__ cnt,
                                                 int* __restrict__ cand,
                                                 float* __restrict__ out,
                                                 double* __restrict__ partials) {
  __shared__ double xs[DIN];
  __shared__ double red[256];
  __shared__ double zd[PDIM];
  __shared__ int idx2[2];   // [0]=new, [1]=old
  const int t = threadIdx.x;
  const int n = *cnt;
  for (int it = blockIdx.x; it < n; it += gridDim.x) {
    const int row = list[it];
    __syncthreads();
    for (int i = t; i < DIN; i += 256) xs[i] = (double)A[(size_t)row * DIN + i];
    __syncthreads();
    double s = 0.0;
    for (int i = t; i < DIN; i += 256) s += xs[i] * xs[i];
    red[t] = s; __syncthreads();
    for (int m = 128; m; m >>= 1) { if (t < m) red[t] += red[t + m]; __syncthreads(); }
    const double inv = 1.0 / fmax(sqrt(red[0]), 1e-12);

    double gj = 0.0;
#pragma unroll 8
    for (int k = 0; k < DIN; ++k) gj += xs[k] * (double)W[(size_t)k * PDIM + t];
    const double h = gj * inv + (double)bvec[t];

    __syncthreads(); red[t] = h; __syncthreads();
    for (int m = 128; m; m >>= 1) { if (t < m) red[t] += red[t + m]; __syncthreads(); }
    const double mu = red[0] * (1.0 / 256.0);
    const double d = h - mu;
    __syncthreads(); red[t] = d * d; __syncthreads();
    for (int m = 128; m; m >>= 1) { if (t < m) red[t] += red[t + m]; __syncthreads(); }
    const double invs = 1.0 / sqrt(red[0] * (1.0 / 256.0) + 1e-5);
    const double zp = d * invs * (double)gamma[t] + (double)beta[t];
    __syncthreads(); red[t] = zp * zp; __syncthreads();
    for (int m = 128; m; m >>= 1) { if (t < m) red[t] += red[t + m]; __syncthreads(); }
    const double zn = 1.0 / fmax(sqrt(red[0]), 1e-12);
    const double z = zp * zn;
    zd[t] = z;
    __syncthreads(); red[t] = z * z; __syncthreads();
    for (int m = 128; m; m >>= 1) { if (t < m) red[t] += red[t + m]; __syncthreads(); }
    const double zz = red[0];
    __syncthreads();
    if (t < KCB) {
      double p = 0.0, cc = 0.0;
      for (int c = 0; c < PDIM; ++c) {
        double cv = (double)C[(size_t)t * PDIM + c];
        p += zd[c] * cv; cc += cv * cv;
      }
      red[t] = zz - 2.0 * p + cc;   // == sum((c_t - z)^2) in exact arithmetic
    }
    __syncthreads();
    if (t == 0) {
      double best = red[0]; int bi = 0;
      for (int k = 1; k < KCB; ++k) if (red[k] < best) { best = red[k]; bi = k; }
      const int old = cand[row];
      idx2[0] = bi; idx2[1] = old;
      if (bi != old) {
        cand[row] = bi;
        out[(size_t)NB * PDIM + row] = (float)bi;
        atomicAdd(&partials[row >> 2], red[bi] - red[old]);
      }
    }
    __syncthreads();
    if (idx2[0] != idx2[1])
      out[(size_t)row * PDIM + t] = C[(size_t)idx2[0] * PDIM + t];
    __syncthreads();
  }
}

// K6: reduce loss partials, write scalar.
__global__ __launch_bounds__(256) void k6_finalize(const double* __restrict__ partials,
                                                   float* __restrict__ out) {
  __shared__ double red[256];
  const int t = threadIdx.x;
  double s = 0.0;
  for (int i = t; i < NB / 4; i += 256) s += partials[i];
  red[t] = s; __syncthreads();
  for (int m = 128; m; m >>= 1) { if (t < m) red[t] += red[t + m]; __syncthreads(); }
  if (t == 0)
    out[(size_t)NB * PDIM + NB] = (float)(0.25 * red[0] / ((double)NB * (double)PDIM));
}

extern "C" void kernel_launch(void* const* d_in, const int* in_sizes, int n_in,
                              void* d_out, int out_size, void* d_ws, size_t ws_size,
                              hipStream_t stream) {
  const float* z_frame  = (const float*)d_in[0];
  const float* W        = (const float*)d_in[1];
  const float* bvec     = (const float*)d_in[2];
  const float* gamma    = (const float*)d_in[3];
  const float* beta     = (const float*)d_in[4];
  const float* codebook = (const float*)d_in[5];
  float* out = (float*)d_out;

  char* ws = (char*)d_ws;
  int*    cnt      = (int*)(ws + OFF_CNT);
  int*    cand     = (int*)(ws + OFF_CAND);
  int*    list     = (int*)(ws + OFF_LIST);
  double* partials = (double*)(ws + OFF_PART);
  float*  g        = (float*)(ws + OFF_G);

  hipMemsetAsync(ws + OFF_CNT, 0, 64, stream);

  k2_gemm<<<NB / 64, 256, 0, stream>>>(z_frame, W, g);
  k3_epilogue<<<NB / 4, 256, 0, stream>>>(g, bvec, gamma, beta, codebook,
                                          out, cand, list, cnt, partials);
  k4_refine<<<256, 256, 0, stream>>>(z_frame, W, bvec, gamma, beta, codebook,
                                     list, cnt, cand, out, partials);
  k6_finalize<<<partials == nullptr ? 1 : 1, 256, 0, stream>>>(partials, out);
}